// Round 1
// baseline (425.472 us; speedup 1.0000x reference)
//
#include <hip/hip_runtime.h>
#include <math.h>

typedef _Float16 f16x8 __attribute__((ext_vector_type(8)));
typedef float    f32x4 __attribute__((ext_vector_type(4)));
typedef _Float16 f16x2 __attribute__((ext_vector_type(2)));
typedef __fp16   fp16x2 __attribute__((ext_vector_type(2)));

#define B_TOT 2048
#define LSEQ  512
#define NS    16
#define NCH   2          // independent 16-sample chains per block -> 2 waves/SIMD
#define LOG2E 1.44269504088896f
#define LN2   0.69314718055995f

#define MFMA16(A, B, C) __builtin_amdgcn_mfma_f32_16x16x32_f16((A), (B), (C), 0, 0, 0)

__device__ __forceinline__ unsigned int pkrtz(float a, float b) {
    fp16x2 p = __builtin_amdgcn_cvt_pkrtz(a, b);
    return __builtin_bit_cast(unsigned int, p);
}

__global__ __launch_bounds__(512, 1)
void lstm_v14_kernel(const int* __restrict__ s,
                     const float* __restrict__ W0, const float* __restrict__ b0,
                     const float* __restrict__ Wi, const float* __restrict__ Wh,
                     const float* __restrict__ bh, const float* __restrict__ Wa,
                     const float* __restrict__ ba, const float* __restrict__ Wp,
                     const float* __restrict__ bp, float* __restrict__ out)
{
    const int tid  = threadIdx.x;
    const int ch   = tid >> 8;     // chain 0/1 (waves 0-3 = chain0, 4-7 = chain1)
    const int ct   = tid & 255;    // tid within chain
    const int w    = ct >> 6;      // wave 0..3 within chain: feature block 16w..16w+15
    const int lane = tid & 63;
    const int n    = lane & 15;    // sample (MFMA N / D-col)
    const int q    = lane >> 4;
    const int b0s  = blockIdx.x * (NS * NCH) + ch * NS;

    // h layout per chain: chunk c (features 8c..8c+7) of sample n = 4 consecutive
    // dwords at 4n + 64*(c&1) + 128*(c>>1) -> 1x ds_write_b64, 2x ds_read_b128,
    // <=2 lanes/bank per phase (free, m136).
    __shared__ __align__(16) unsigned int HhD[NCH][2][512];  //  8 KB
    __shared__ unsigned short TOKB[NCH][LSEQ + 2];           //  2 KB
    __shared__ unsigned char  SRAW[NCH][NS][LSEQ];           // 16 KB
    __shared__ _Float16 DBUF[NCH][LSEQ][NS];                 // 32 KB
    __shared__ float PART[NCH][16][NS];                      //  2 KB

    // ---- stage tokens (coalesced in t, per chain) ----
    for (int i = ct; i < NS * LSEQ; i += 256)
        SRAW[ch][i >> 9][i & 511] = (unsigned char)s[(b0s + (i >> 9)) * LSEQ + (i & 511)];
    __syncthreads();
    for (int u = ct; u <= LSEQ; u += 256) {
        unsigned int mask = 0;
        if (u >= 1) {
            #pragma unroll
            for (int m = 0; m < NS; ++m)
                mask |= ((unsigned int)SRAW[ch][m][u - 1]) << m;
        }
        TOKB[ch][u] = (unsigned short)mask;
    }

    // ---- A-frags: scaled Wh^T ----
    f16x8 awh[4][2];
    #pragma unroll
    for (int g = 0; g < 4; ++g) {
        const float sc  = (g == 2) ? (2.0f * LOG2E) : (-LOG2E);
        const int   col = 64 * g + 16 * w + n;
        #pragma unroll
        for (int c = 0; c < 2; ++c)
            #pragma unroll
            for (int j = 0; j < 8; ++j)
                awh[g][c][j] = (_Float16)(Wh[(32 * c + 8 * q + j) * 256 + col] * sc);
    }

    // ---- d-GEMM A-frag: row 0 = Wa[:,1]-Wa[:,0] ----
    f16x8 awd[2];
    #pragma unroll
    for (int c = 0; c < 2; ++c)
        #pragma unroll
        for (int j = 0; j < 8; ++j) {
            int k = 32 * c + 8 * q + j;
            awd[c][j] = (_Float16)((n == 0) ? (Wa[2 * k + 1] - Wa[2 * k]) : 0.0f);
        }
    const float dba = ba[1] - ba[0];

    // ---- p0/dp (scaled), kept as f32x4 for packed-FMA C-init ----
    f32x4 p0q[4], dpq[4];
    {
        float a0[4][4], a1[4][4];
        #pragma unroll
        for (int g = 0; g < 4; ++g)
            #pragma unroll
            for (int r = 0; r < 4; ++r) {
                float bb = bh[64 * g + 16 * w + 4 * q + r];
                a0[g][r] = bb; a1[g][r] = bb;
            }
        for (int f = 0; f < 64; ++f) {
            float wb0 = W0[f]      + b0[f];
            float wb1 = W0[64 + f] + b0[f];
            #pragma unroll
            for (int g = 0; g < 4; ++g) {
                const float4 wi4 = *(const float4*)&Wi[f * 256 + 64 * g + 16 * w + 4 * q];
                #pragma unroll
                for (int r = 0; r < 4; ++r) {
                    float wi = (&wi4.x)[r];
                    a0[g][r] = fmaf(wb0, wi, a0[g][r]);
                    a1[g][r] = fmaf(wb1, wi, a1[g][r]);
                }
            }
        }
        #pragma unroll
        for (int g = 0; g < 4; ++g) {
            const float sc = (g == 2) ? (2.0f * LOG2E) : (-LOG2E);
            #pragma unroll
            for (int r = 0; r < 4; ++r) {
                p0q[g][r] = a0[g][r] * sc;
                dpq[g][r] = (a1[g][r] - a0[g][r]) * sc;
            }
        }
    }

    __syncthreads();   // TOKB ready

    // ---- loop-invariant LDS dword addresses (within chain's HhD) ----
    const int wAddr = 4 * n + 64 * (q >> 1) + 128 * w + 2 * (q & 1);
    const int rAddr = 4 * n + 64 * (q & 1) + 128 * (q >> 1);

    // ---- state ----
    float h4[4] = {0, 0, 0, 0}, c4[4] = {0, 0, 0, 0};
    f32x4 ci[4];
    #pragma unroll
    for (int g = 0; g < 4; ++g) ci[g] = p0q[g];

    // deferred d-result (written one step late, off the straggler's barrier path)
    float dpend = 0.0f;
    int   tpend = -1;

    #pragma unroll 4
    for (int v = 0; v <= LSEQ; ++v) {
        const int p = v & 1;
        unsigned int* __restrict__ hb = &HhD[ch][p][0];

        // publish h_{v-1}: one ds_write_b64
        uint2 hw;
        hw.x = pkrtz(h4[0], h4[1]);
        hw.y = pkrtz(h4[2], h4[3]);
        *(uint2*)&hb[wAddr] = hw;
        __syncthreads();

        // flush last rotation's d-result (visibility deadline = post-loop barrier)
        if (tpend >= 0) {
            if (lane < 16) DBUF[ch][tpend][n] = (_Float16)dpend;
            tpend = -1;
        }

        // B-frags: two ds_read_b128
        uint4 r0 = *(const uint4*)&hb[rAddr];
        uint4 r1 = *(const uint4*)&hb[rAddr + 256];
        const f16x8 bf0 = __builtin_bit_cast(f16x8, r0);
        const f16x8 bf1 = __builtin_bit_cast(f16x8, r1);

        const unsigned int tokm_next = (v < LSEQ) ? (unsigned int)TOKB[ch][v + 1] : 0u;

        // gates GEMM
        f32x4 acc0 = ci[0], acc1 = ci[1], acc2 = ci[2], acc3 = ci[3];
        acc0 = MFMA16(awh[0][0], bf0, acc0);
        acc1 = MFMA16(awh[1][0], bf0, acc1);
        acc2 = MFMA16(awh[2][0], bf0, acc2);
        acc3 = MFMA16(awh[3][0], bf0, acc3);
        acc0 = MFMA16(awh[0][1], bf1, acc0);
        acc1 = MFMA16(awh[1][1], bf1, acc1);
        acc2 = MFMA16(awh[2][1], bf1, acc2);
        acc3 = MFMA16(awh[3][1], bf1, acc3);

        // rotating wave: raw logit-diff for step v-1; write deferred one step.
        // unroll-4 makes (v & 3) a compile-time constant -> uniform compare.
        if (v >= 1 && w == (v & 3)) {
            f32x4 da = (f32x4){dba, dba, dba, dba};
            da = MFMA16(awd[0], bf0, da);
            da = MFMA16(awd[1], bf1, da);
            dpend = da[0];
            tpend = v - 1;
        }

        // C-init for next iter: vector form -> v_pk_fma_f32 (2 floats/inst)
        const float sel = (float)((tokm_next >> n) & 1u);
        const f32x4 sel4 = {sel, sel, sel, sel};
        #pragma unroll
        for (int g = 0; g < 4; ++g)
            ci[g] = dpq[g] * sel4 + p0q[g];

        // activations: 5 exp2 + 2 rcp per row (algebraic minimum)
        #pragma unroll
        for (int r = 0; r < 4; ++r) {
            float ei = __builtin_amdgcn_exp2f(acc0[r]);               // e^{-i}
            float ef = __builtin_amdgcn_exp2f(acc1[r]);               // e^{-f}
            float eg = __builtin_amdgcn_exp2f(acc2[r]);               // e^{2g}
            float eo = __builtin_amdgcn_exp2f(acc3[r]);               // e^{-o}
            float P  = (1.0f + ei) * (eg + 1.0f);
            float F  = 1.0f + ef;
            float R2 = __builtin_amdgcn_rcpf(P * F);
            float cn = fmaf(c4[r] * P, R2, (eg - 1.0f) * F * R2);
            c4[r] = cn;
            float ec = __builtin_amdgcn_exp2f(fminf(cn * (2.0f * LOG2E), 60.f));
            float Ro = __builtin_amdgcn_rcpf((1.0f + eo) * (ec + 1.0f));
            h4[r] = (ec - 1.0f) * Ro;
        }
    }

    // ---- tail: flush pending d, publish h_512 into buffer 1 ----
    if (tpend >= 0 && lane < 16) DBUF[ch][tpend][n] = (_Float16)dpend;
    {
        uint2 hw;
        hw.x = pkrtz(h4[0], h4[1]);
        hw.y = pkrtz(h4[2], h4[3]);
        *(uint2*)&HhD[ch][1][wAddr] = hw;
    }
    __syncthreads();

    // ---- amp post-pass (per chain, 256 threads) ----
    {
        const int nn = ct & 15;
        const int cc = ct >> 4;
        float a = 0.0f;
        #pragma unroll 4
        for (int k = 0; k < 32; ++k) {
            int t = cc * 32 + k;
            float d = (float)DBUF[ch][t][nn];
            float x = SRAW[ch][nn][t] ? -d : d;
            float e = __builtin_amdgcn_exp2f(-fabsf(x) * LOG2E);
            a += fmaxf(x, 0.0f) + __builtin_amdgcn_logf(1.0f + e) * LN2;
        }
        PART[ch][cc][nn] = a;
    }
    __syncthreads();

    if (ct < 16) {
        float ssum = 0.0f;
        #pragma unroll
        for (int c = 0; c < 16; ++c) ssum += PART[ch][c][ct];
        out[b0s + ct] = -0.5f * ssum;              // planar real
    }

    // ---- phase: wave 0 of each chain; lane (n,q) covers features 16q..16q+15 ----
    if (w == 0) {
        float ph = 0.0f;
        #pragma unroll
        for (int d = 0; d < 4; ++d) {
            unsigned int ua = HhD[ch][1][4 * n + 128 * q + d];
            unsigned int ub = HhD[ch][1][4 * n + 64 + 128 * q + d];
            f16x2 ha  = __builtin_bit_cast(f16x2, ua);
            f16x2 hb2 = __builtin_bit_cast(f16x2, ub);
            ph = fmaf((float)ha[0], Wp[16 * q + 2 * d],
                 fmaf((float)ha[1], Wp[16 * q + 2 * d + 1], ph));
            ph = fmaf((float)hb2[0], Wp[16 * q + 8 + 2 * d],
                 fmaf((float)hb2[1], Wp[16 * q + 8 + 2 * d + 1], ph));
        }
        ph += __shfl_xor(ph, 16, 64);
        ph += __shfl_xor(ph, 32, 64);
        if (q == 0) out[B_TOT + b0s + n] = ph + bp[0];   // planar imag
    }
}

extern "C" void kernel_launch(void* const* d_in, const int* in_sizes, int n_in,
                              void* d_out, int out_size, void* d_ws, size_t ws_size,
                              hipStream_t stream) {
    const int*   s  = (const int*)  d_in[0];
    const float* W0 = (const float*)d_in[1];
    const float* b0 = (const float*)d_in[2];
    const float* Wi = (const float*)d_in[3];
    const float* Wh = (const float*)d_in[4];
    const float* bh = (const float*)d_in[5];
    const float* Wa = (const float*)d_in[6];
    const float* ba = (const float*)d_in[7];
    const float* Wp = (const float*)d_in[8];
    const float* bp = (const float*)d_in[9];
    float* out = (float*)d_out;

    dim3 grid(B_TOT / (NS * NCH));  // 64 WGs x 8 waves: 2 independent chains/CU,
    dim3 block(512);                //  2 waves/SIMD fill each other's stall slots
    lstm_v14_kernel<<<grid, block, 0, stream>>>(s, W0, b0, Wi, Wh, bh,
                                                Wa, ba, Wp, bp, out);
}

// Round 2
// 333.367 us; speedup vs baseline: 1.2763x; 1.2763x over previous
//
#include <hip/hip_runtime.h>
#include <math.h>

typedef _Float16 f16x8 __attribute__((ext_vector_type(8)));
typedef float    f32x4 __attribute__((ext_vector_type(4)));
typedef _Float16 f16x2 __attribute__((ext_vector_type(2)));
typedef __fp16   fp16x2 __attribute__((ext_vector_type(2)));

#define B_TOT 2048
#define LSEQ  512
#define NS    16
#define LOG2E 1.44269504088896f
#define LN2   0.69314718055995f

#define MFMA16(A, B, C) __builtin_amdgcn_mfma_f32_16x16x32_f16((A), (B), (C), 0, 0, 0)

__device__ __forceinline__ unsigned int pkrtz(float a, float b) {
    fp16x2 p = __builtin_amdgcn_cvt_pkrtz(a, b);
    return __builtin_bit_cast(unsigned int, p);
}

__global__ __launch_bounds__(256, 1)
void lstm_v15_kernel(const int* __restrict__ s,
                     const float* __restrict__ W0, const float* __restrict__ b0,
                     const float* __restrict__ Wi, const float* __restrict__ Wh,
                     const float* __restrict__ bh, const float* __restrict__ Wa,
                     const float* __restrict__ ba, const float* __restrict__ Wp,
                     const float* __restrict__ bp, float* __restrict__ out)
{
    const int tid  = threadIdx.x;
    const int w    = tid >> 6;     // wave 0..3: feature block 16w..16w+15 (all 4 gates)
    const int lane = tid & 63;
    const int n    = lane & 15;    // sample (MFMA N / D-col)
    const int q    = lane >> 4;
    const int b0s  = blockIdx.x * NS;

    // h layout: chunk c (features 8c..8c+7) of sample n = 4 consecutive dwords
    // at 4n + 64*(c&1) + 128*(c>>1) -> publish 1x ds_write_b64, read 2x b128,
    // <=2 lanes/bank per phase (free, m136).
    __shared__ __align__(16) unsigned int HhD[2][512];  //  4 KB
    __shared__ unsigned short TOKB[LSEQ + 2];           //  1 KB
    __shared__ unsigned char  SRAW[NS][LSEQ];           //  8 KB
    __shared__ _Float16 DBUF[LSEQ][NS];                 // 16 KB
    __shared__ float PART[16][NS];                      //  1 KB

    // ---- stage tokens (coalesced in t) ----
    for (int i = tid; i < NS * LSEQ; i += 256)
        SRAW[i >> 9][i & 511] = (unsigned char)s[(b0s + (i >> 9)) * LSEQ + (i & 511)];
    __syncthreads();
    for (int u = tid; u <= LSEQ; u += 256) {
        unsigned int mask = 0;
        if (u >= 1) {
            #pragma unroll
            for (int m = 0; m < NS; ++m)
                mask |= ((unsigned int)SRAW[m][u - 1]) << m;
        }
        TOKB[u] = (unsigned short)mask;
    }

    // ---- A-frags: scaled Wh^T ----
    f16x8 awh[4][2];
    #pragma unroll
    for (int g = 0; g < 4; ++g) {
        const float sc  = (g == 2) ? (2.0f * LOG2E) : (-LOG2E);
        const int   col = 64 * g + 16 * w + n;
        #pragma unroll
        for (int c = 0; c < 2; ++c)
            #pragma unroll
            for (int j = 0; j < 8; ++j)
                awh[g][c][j] = (_Float16)(Wh[(32 * c + 8 * q + j) * 256 + col] * sc);
    }

    // ---- d-GEMM A-frag: row 0 = Wa[:,1]-Wa[:,0] ----
    f16x8 awd[2];
    #pragma unroll
    for (int c = 0; c < 2; ++c)
        #pragma unroll
        for (int j = 0; j < 8; ++j) {
            int k = 32 * c + 8 * q + j;
            awd[c][j] = (_Float16)((n == 0) ? (Wa[2 * k + 1] - Wa[2 * k]) : 0.0f);
        }
    const float dba = ba[1] - ba[0];

    // ---- p0/dp (scaled), kept as f32x4 for packed-FMA C-init ----
    f32x4 p0q[4], dpq[4];
    {
        float a0[4][4], a1[4][4];
        #pragma unroll
        for (int g = 0; g < 4; ++g)
            #pragma unroll
            for (int r = 0; r < 4; ++r) {
                float bb = bh[64 * g + 16 * w + 4 * q + r];
                a0[g][r] = bb; a1[g][r] = bb;
            }
        for (int f = 0; f < 64; ++f) {
            float wb0 = W0[f]      + b0[f];
            float wb1 = W0[64 + f] + b0[f];
            #pragma unroll
            for (int g = 0; g < 4; ++g) {
                const float4 wi4 = *(const float4*)&Wi[f * 256 + 64 * g + 16 * w + 4 * q];
                #pragma unroll
                for (int r = 0; r < 4; ++r) {
                    float wi = (&wi4.x)[r];
                    a0[g][r] = fmaf(wb0, wi, a0[g][r]);
                    a1[g][r] = fmaf(wb1, wi, a1[g][r]);
                }
            }
        }
        #pragma unroll
        for (int g = 0; g < 4; ++g) {
            const float sc = (g == 2) ? (2.0f * LOG2E) : (-LOG2E);
            #pragma unroll
            for (int r = 0; r < 4; ++r) {
                p0q[g][r] = a0[g][r] * sc;
                dpq[g][r] = (a1[g][r] - a0[g][r]) * sc;
            }
        }
    }

    __syncthreads();   // TOKB ready

    // ---- loop-invariant LDS dword addresses ----
    const int wAddr = 4 * n + 64 * (q >> 1) + 128 * w + 2 * (q & 1);
    const int rAddr = 4 * n + 64 * (q & 1) + 128 * (q >> 1);

    // ---- state ----
    float h4[4] = {0, 0, 0, 0}, c4[4] = {0, 0, 0, 0};
    f32x4 ci[4];
    #pragma unroll
    for (int g = 0; g < 4; ++g) ci[g] = p0q[g];

    // B-frags persist across iterations: the rotating d-GEMM consumes the
    // PREVIOUS step's frags inside the barrier-wait window (off the post-
    // barrier critical path). dpend flushes one iteration later, also
    // pre-barrier (visibility deadline = post-loop barrier).
    f16x8 bf0 = {}, bf1 = {};
    float dpend = 0.0f;

    #pragma unroll 4
    for (int v = 0; v <= LSEQ; ++v) {
        const int p = v & 1;
        unsigned int* __restrict__ hb = &HhD[p][0];

        // ---- pre-barrier region (hidden under barrier wait) ----
        // flush d-result for t = v-3 (computed last rotation by this wave)
        if (v >= 3 && w == ((v - 1) & 3)) {
            if (lane < 16) DBUF[v - 3][n] = (_Float16)dpend;
        }
        // rotating wave: raw logit-diff for t = v-2 from PREVIOUS bf regs
        // (unroll-4 makes (v & 3) a compile-time constant -> uniform compare)
        if (v >= 2 && w == (v & 3)) {
            f32x4 da = (f32x4){dba, dba, dba, dba};
            da = MFMA16(awd[0], bf0, da);
            da = MFMA16(awd[1], bf1, da);
            dpend = da[0];
        }
        // publish h_{v-1}: one ds_write_b64
        uint2 hw;
        hw.x = pkrtz(h4[0], h4[1]);
        hw.y = pkrtz(h4[2], h4[3]);
        *(uint2*)&hb[wAddr] = hw;
        __syncthreads();

        // ---- post-barrier critical path: reads FIRST ----
        uint4 r0 = *(const uint4*)&hb[rAddr];
        uint4 r1 = *(const uint4*)&hb[rAddr + 256];
        bf0 = __builtin_bit_cast(f16x8, r0);
        bf1 = __builtin_bit_cast(f16x8, r1);

        // gates GEMM
        f32x4 acc0 = ci[0], acc1 = ci[1], acc2 = ci[2], acc3 = ci[3];
        acc0 = MFMA16(awh[0][0], bf0, acc0);
        acc1 = MFMA16(awh[1][0], bf0, acc1);
        acc2 = MFMA16(awh[2][0], bf0, acc2);
        acc3 = MFMA16(awh[3][0], bf0, acc3);
        acc0 = MFMA16(awh[0][1], bf1, acc0);
        acc1 = MFMA16(awh[1][1], bf1, acc1);
        acc2 = MFMA16(awh[2][1], bf1, acc2);
        acc3 = MFMA16(awh[3][1], bf1, acc3);

        // token mask for next step (hides under MFMA/read latency)
        const unsigned int tokm_next = (v < LSEQ) ? (unsigned int)TOKB[v + 1] : 0u;

        // C-init for next iter: vector form -> v_pk_fma_f32 (2 floats/inst)
        const float sel = (float)((tokm_next >> n) & 1u);
        const f32x4 sel4 = {sel, sel, sel, sel};
        #pragma unroll
        for (int g = 0; g < 4; ++g)
            ci[g] = dpq[g] * sel4 + p0q[g];

        // activations: 5 exp2 + 2 rcp per row (algebraic minimum)
        #pragma unroll
        for (int r = 0; r < 4; ++r) {
            float ei = __builtin_amdgcn_exp2f(acc0[r]);               // e^{-i}
            float ef = __builtin_amdgcn_exp2f(acc1[r]);               // e^{-f}
            float eg = __builtin_amdgcn_exp2f(acc2[r]);               // e^{2g}
            float eo = __builtin_amdgcn_exp2f(acc3[r]);               // e^{-o}
            float P  = (1.0f + ei) * (eg + 1.0f);
            float F  = 1.0f + ef;
            float R2 = __builtin_amdgcn_rcpf(P * F);
            float cn = fmaf(c4[r] * P, R2, (eg - 1.0f) * F * R2);
            c4[r] = cn;
            float ec = __builtin_amdgcn_exp2f(fminf(cn * (2.0f * LOG2E), 60.f));
            float Ro = __builtin_amdgcn_rcpf((1.0f + eo) * (ec + 1.0f));
            h4[r] = (ec - 1.0f) * Ro;
        }
    }

    // ---- tail: pending d-results t=510 (wave 0) and t=511 (wave 1, from
    // final bf regs = h_511), then publish h_512 into buffer 1 ----
    if (w == 0 && lane < 16) DBUF[510][n] = (_Float16)dpend;
    if (w == 1) {
        f32x4 da = (f32x4){dba, dba, dba, dba};
        da = MFMA16(awd[0], bf0, da);
        da = MFMA16(awd[1], bf1, da);
        if (lane < 16) DBUF[511][n] = (_Float16)da[0];
    }
    {
        uint2 hw;
        hw.x = pkrtz(h4[0], h4[1]);
        hw.y = pkrtz(h4[2], h4[3]);
        *(uint2*)&HhD[1][wAddr] = hw;
    }
    __syncthreads();

    // ---- amp post-pass ----
    {
        const int nn = tid & 15;
        const int ch = tid >> 4;
        float a = 0.0f;
        #pragma unroll 4
        for (int k = 0; k < 32; ++k) {
            int t = ch * 32 + k;
            float d = (float)DBUF[t][nn];
            float x = SRAW[nn][t] ? -d : d;
            float e = __builtin_amdgcn_exp2f(-fabsf(x) * LOG2E);
            a += fmaxf(x, 0.0f) + __builtin_amdgcn_logf(1.0f + e) * LN2;
        }
        PART[ch][nn] = a;
    }
    __syncthreads();

    if (tid < 16) {
        float ssum = 0.0f;
        #pragma unroll
        for (int c = 0; c < 16; ++c) ssum += PART[c][tid];
        out[b0s + tid] = -0.5f * ssum;              // planar real
    }

    // ---- phase: wave 0; lane (n,q) covers features 16q..16q+15 of sample n
    if (w == 0) {
        float ph = 0.0f;
        #pragma unroll
        for (int d = 0; d < 4; ++d) {
            unsigned int ua = HhD[1][4 * n + 128 * q + d];
            unsigned int ub = HhD[1][4 * n + 64 + 128 * q + d];
            f16x2 ha  = __builtin_bit_cast(f16x2, ua);
            f16x2 hb2 = __builtin_bit_cast(f16x2, ub);
            ph = fmaf((float)ha[0], Wp[16 * q + 2 * d],
                 fmaf((float)ha[1], Wp[16 * q + 2 * d + 1], ph));
            ph = fmaf((float)hb2[0], Wp[16 * q + 8 + 2 * d],
                 fmaf((float)hb2[1], Wp[16 * q + 8 + 2 * d + 1], ph));
        }
        ph += __shfl_xor(ph, 16, 64);
        ph += __shfl_xor(ph, 32, 64);
        if (q == 0) out[B_TOT + b0s + n] = ph + bp[0];   // planar imag
    }
}

extern "C" void kernel_launch(void* const* d_in, const int* in_sizes, int n_in,
                              void* d_out, int out_size, void* d_ws, size_t ws_size,
                              hipStream_t stream) {
    const int*   s  = (const int*)  d_in[0];
    const float* W0 = (const float*)d_in[1];
    const float* b0 = (const float*)d_in[2];
    const float* Wi = (const float*)d_in[3];
    const float* Wh = (const float*)d_in[4];
    const float* bh = (const float*)d_in[5];
    const float* Wa = (const float*)d_in[6];
    const float* ba = (const float*)d_in[7];
    const float* Wp = (const float*)d_in[8];
    const float* bp = (const float*)d_in[9];
    float* out = (float*)d_out;

    dim3 grid(B_TOT / NS);   // 128 WGs x 4 waves: 1 wave/SIMD, chains are the
    dim3 block(256);         // latency-critical path (wall = 513 * L_step)
    lstm_v15_kernel<<<grid, block, 0, stream>>>(s, W0, b0, Wi, Wh, bh,
                                                Wa, ba, Wp, bp, out);
}

// Round 3
// 277.148 us; speedup vs baseline: 1.5352x; 1.2028x over previous
//
#include <hip/hip_runtime.h>
#include <math.h>

typedef _Float16 f16x8 __attribute__((ext_vector_type(8)));
typedef float    f32x4 __attribute__((ext_vector_type(4)));
typedef _Float16 f16x2 __attribute__((ext_vector_type(2)));
typedef __fp16   fp16x2 __attribute__((ext_vector_type(2)));

#define B_TOT 2048
#define LSEQ  512
#define NS    8            // samples per block; 256 blocks -> all 256 CUs
#define LOG2E 1.44269504088896f
#define LN2   0.69314718055995f

#define MFMA16(A, B, C) __builtin_amdgcn_mfma_f32_16x16x32_f16((A), (B), (C), 0, 0, 0)

__device__ __forceinline__ unsigned int pkrtz(float a, float b) {
    fp16x2 p = __builtin_amdgcn_cvt_pkrtz(a, b);
    return __builtin_bit_cast(unsigned int, p);
}

__global__ __launch_bounds__(256, 1)
void lstm_v16_kernel(const int* __restrict__ s,
                     const float* __restrict__ W0, const float* __restrict__ b0,
                     const float* __restrict__ Wi, const float* __restrict__ Wh,
                     const float* __restrict__ bh, const float* __restrict__ Wa,
                     const float* __restrict__ ba, const float* __restrict__ Wp,
                     const float* __restrict__ bp, float* __restrict__ out)
{
    const int tid  = threadIdx.x;
    const int w    = tid >> 6;     // wave 0..3: feature block 16w..16w+15 (all 4 gates)
    const int lane = tid & 63;
    const int n    = lane & 15;    // MFMA column; samples duplicated: col n == col n+8
    const int q    = lane >> 4;
    const int ns   = n & 7;        // sample index
    const int hi   = n >> 3;       // row-half: lane n<8 -> acc rows {0,1}, n>=8 -> {2,3}
    const int b0s  = blockIdx.x * NS;

    // h layout: sample sN, chunk c (features 8c..8c+7) = 4 dwords at
    // 4*sN + 64*(c&1) + 128*(c>>1).  Each lane publishes ONE dword (2 features),
    // reads 2x ds_read_b128; cols n/n+8 read the same address (broadcast, free).
    __shared__ __align__(16) unsigned int HhD[2][512];  //  4 KB
    __shared__ unsigned short TOKB[LSEQ + 2];           //  1 KB
    __shared__ unsigned char  SRAW[NS][LSEQ];           //  4 KB
    __shared__ _Float16 DBUF[LSEQ][NS];                 //  8 KB
    __shared__ float PART[32][NS];                      //  1 KB

    // ---- stage tokens (coalesced in t) ----
    for (int i = tid; i < NS * LSEQ; i += 256)
        SRAW[i >> 9][i & 511] = (unsigned char)s[(b0s + (i >> 9)) * LSEQ + (i & 511)];
    __syncthreads();
    for (int u = tid; u <= LSEQ; u += 256) {
        unsigned int mask = 0;
        if (u >= 1) {
            #pragma unroll
            for (int m = 0; m < NS; ++m)
                mask |= ((unsigned int)SRAW[m][u - 1]) << m;
        }
        TOKB[u] = (unsigned short)mask;
    }

    // ---- A-frags: scaled Wh^T (row m = n, full 16 rows) ----
    f16x8 awh[4][2];
    #pragma unroll
    for (int g = 0; g < 4; ++g) {
        const float sc  = (g == 2) ? (2.0f * LOG2E) : (-LOG2E);
        const int   col = 64 * g + 16 * w + n;
        #pragma unroll
        for (int c = 0; c < 2; ++c)
            #pragma unroll
            for (int j = 0; j < 8; ++j)
                awh[g][c][j] = (_Float16)(Wh[(32 * c + 8 * q + j) * 256 + col] * sc);
    }

    // ---- d-GEMM A-frag: row 0 = Wa[:,1]-Wa[:,0] ----
    f16x8 awd[2];
    #pragma unroll
    for (int c = 0; c < 2; ++c)
        #pragma unroll
        for (int j = 0; j < 8; ++j) {
            int k = 32 * c + 8 * q + j;
            awd[c][j] = (_Float16)((n == 0) ? (Wa[2 * k + 1] - Wa[2 * k]) : 0.0f);
        }
    const float dba = ba[1] - ba[0];

    // ---- p0/dp (scaled), full 4 rows per lane (MFMA C operand) ----
    f32x4 p0q[4], dpq[4];
    {
        float a0[4][4], a1[4][4];
        #pragma unroll
        for (int g = 0; g < 4; ++g)
            #pragma unroll
            for (int r = 0; r < 4; ++r) {
                float bb = bh[64 * g + 16 * w + 4 * q + r];
                a0[g][r] = bb; a1[g][r] = bb;
            }
        for (int f = 0; f < 64; ++f) {
            float wb0 = W0[f]      + b0[f];
            float wb1 = W0[64 + f] + b0[f];
            #pragma unroll
            for (int g = 0; g < 4; ++g) {
                const float4 wi4 = *(const float4*)&Wi[f * 256 + 64 * g + 16 * w + 4 * q];
                #pragma unroll
                for (int r = 0; r < 4; ++r) {
                    float wi = (&wi4.x)[r];
                    a0[g][r] = fmaf(wb0, wi, a0[g][r]);
                    a1[g][r] = fmaf(wb1, wi, a1[g][r]);
                }
            }
        }
        #pragma unroll
        for (int g = 0; g < 4; ++g) {
            const float sc = (g == 2) ? (2.0f * LOG2E) : (-LOG2E);
            #pragma unroll
            for (int r = 0; r < 4; ++r) {
                p0q[g][r] = a0[g][r] * sc;
                dpq[g][r] = (a1[g][r] - a0[g][r]) * sc;
            }
        }
    }

    __syncthreads();   // TOKB ready

    // ---- loop-invariant LDS dword addresses ----
    // write: feature f = 16w + 4q + (2*hi + rr) -> chunk c = 2w + (q>>1),
    //        dword-in-chunk = 2*(q&1) + hi  -> one dword per lane
    const int wAddr = 4 * ns + 64 * (q >> 1) + 128 * w + 2 * (q & 1) + hi;
    const int rAddr = 4 * ns + 64 * (q & 1) + 128 * (q >> 1);

    // ---- state: 2 cells per lane (rows 2*hi, 2*hi+1 of col n) ----
    float h2[2] = {0, 0}, c2[2] = {0, 0};
    f32x4 ci[4];
    #pragma unroll
    for (int g = 0; g < 4; ++g) ci[g] = p0q[g];

    float dpend = 0.0f;
    int   tpend = -1;

    #pragma unroll 4
    for (int v = 0; v <= LSEQ; ++v) {
        const int p = v & 1;
        unsigned int* __restrict__ hb = &HhD[p][0];

        // publish h_{v-1}: one ds_write_b32 (head of the serial chain -> first)
        hb[wAddr] = pkrtz(h2[0], h2[1]);
        __syncthreads();

        // flush last rotation's d-result (deadline = post-loop barrier)
        if (tpend >= 0) {
            if (lane < 8) DBUF[tpend][lane] = (_Float16)dpend;
            tpend = -1;
        }

        // B-frags: two ds_read_b128 (cols n / n+8 broadcast same sample)
        uint4 r0 = *(const uint4*)&hb[rAddr];
        uint4 r1 = *(const uint4*)&hb[rAddr + 256];
        const f16x8 bf0 = __builtin_bit_cast(f16x8, r0);
        const f16x8 bf1 = __builtin_bit_cast(f16x8, r1);

        const unsigned int tokm_next = (v < LSEQ) ? (unsigned int)TOKB[v + 1] : 0u;

        // gates GEMM
        f32x4 acc0 = ci[0], acc1 = ci[1], acc2 = ci[2], acc3 = ci[3];
        acc0 = MFMA16(awh[0][0], bf0, acc0);
        acc1 = MFMA16(awh[1][0], bf0, acc1);
        acc2 = MFMA16(awh[2][0], bf0, acc2);
        acc3 = MFMA16(awh[3][0], bf0, acc3);
        acc0 = MFMA16(awh[0][1], bf1, acc0);
        acc1 = MFMA16(awh[1][1], bf1, acc1);
        acc2 = MFMA16(awh[2][1], bf1, acc2);
        acc3 = MFMA16(awh[3][1], bf1, acc3);

        // rotating wave: raw logit-diff for step v-1 (pipelines behind gate MFMAs)
        if (v >= 1 && w == (v & 3)) {
            f32x4 da = (f32x4){dba, dba, dba, dba};
            da = MFMA16(awd[0], bf0, da);
            da = MFMA16(awd[1], bf1, da);
            dpend = da[0];
            tpend = v - 1;
        }

        // C-init for next iter: v_pk_fma_f32
        const float sel = (float)((tokm_next >> ns) & 1u);
        const f32x4 sel4 = {sel, sel, sel, sel};
        #pragma unroll
        for (int g = 0; g < 4; ++g)
            ci[g] = dpq[g] * sel4 + p0q[g];

        // select this lane's 2 rows from the 4-row accumulators
        const bool hb2 = (hi != 0);
        float gi[2] = { hb2 ? acc0[2] : acc0[0], hb2 ? acc0[3] : acc0[1] };
        float gf[2] = { hb2 ? acc1[2] : acc1[0], hb2 ? acc1[3] : acc1[1] };
        float gg[2] = { hb2 ? acc2[2] : acc2[0], hb2 ? acc2[3] : acc2[1] };
        float go[2] = { hb2 ? acc3[2] : acc3[0], hb2 ? acc3[3] : acc3[1] };

        // activations: 5 exp2 + 2 rcp per cell, 2 cells/lane
        #pragma unroll
        for (int rr = 0; rr < 2; ++rr) {
            float ei = __builtin_amdgcn_exp2f(gi[rr]);                // e^{-i}
            float ef = __builtin_amdgcn_exp2f(gf[rr]);                // e^{-f}
            float eg = __builtin_amdgcn_exp2f(gg[rr]);                // e^{2g}
            float eo = __builtin_amdgcn_exp2f(go[rr]);                // e^{-o}
            float P  = (1.0f + ei) * (eg + 1.0f);
            float F  = 1.0f + ef;
            float R2 = __builtin_amdgcn_rcpf(P * F);
            float cn = fmaf(c2[rr] * P, R2, (eg - 1.0f) * F * R2);
            c2[rr] = cn;
            float ec = __builtin_amdgcn_exp2f(fminf(cn * (2.0f * LOG2E), 60.f));
            float Ro = __builtin_amdgcn_rcpf((1.0f + eo) * (ec + 1.0f));
            h2[rr] = (ec - 1.0f) * Ro;
        }
    }

    // ---- tail: flush pending d (wave 0, t=511), publish h_512 into buffer 1 ----
    if (tpend >= 0 && lane < 8) DBUF[tpend][lane] = (_Float16)dpend;
    HhD[1][wAddr] = pkrtz(h2[0], h2[1]);
    __syncthreads();

    // ---- amp post-pass: 8 samples x 512 t, 16 t per thread ----
    {
        const int nn = tid & 7;
        const int cp = tid >> 3;             // 0..31
        float a = 0.0f;
        #pragma unroll 4
        for (int k = 0; k < 16; ++k) {
            int t = cp * 16 + k;
            float d = (float)DBUF[t][nn];
            float x = SRAW[nn][t] ? -d : d;
            float e = __builtin_amdgcn_exp2f(-fabsf(x) * LOG2E);
            a += fmaxf(x, 0.0f) + __builtin_amdgcn_logf(1.0f + e) * LN2;
        }
        PART[cp][nn] = a;
    }
    __syncthreads();

    if (tid < 8) {
        float ssum = 0.0f;
        #pragma unroll
        for (int c = 0; c < 32; ++c) ssum += PART[c][tid];
        out[b0s + tid] = -0.5f * ssum;              // planar real
    }

    // ---- phase: wave 0; lane (n,q) covers features 16q..16q+15 of sample ns
    if (w == 0) {
        float ph = 0.0f;
        #pragma unroll
        for (int d = 0; d < 4; ++d) {
            unsigned int ua = HhD[1][4 * ns + 128 * q + d];
            unsigned int ub = HhD[1][4 * ns + 64 + 128 * q + d];
            f16x2 ha  = __builtin_bit_cast(f16x2, ua);
            f16x2 hc  = __builtin_bit_cast(f16x2, ub);
            ph = fmaf((float)ha[0], Wp[16 * q + 2 * d],
                 fmaf((float)ha[1], Wp[16 * q + 2 * d + 1], ph));
            ph = fmaf((float)hc[0], Wp[16 * q + 8 + 2 * d],
                 fmaf((float)hc[1], Wp[16 * q + 8 + 2 * d + 1], ph));
        }
        ph += __shfl_xor(ph, 16, 64);
        ph += __shfl_xor(ph, 32, 64);
        if (q == 0 && n < 8) out[B_TOT + b0s + n] = ph + bp[0];   // planar imag
    }
}

extern "C" void kernel_launch(void* const* d_in, const int* in_sizes, int n_in,
                              void* d_out, int out_size, void* d_ws, size_t ws_size,
                              hipStream_t stream) {
    const int*   s  = (const int*)  d_in[0];
    const float* W0 = (const float*)d_in[1];
    const float* b0 = (const float*)d_in[2];
    const float* Wi = (const float*)d_in[3];
    const float* Wh = (const float*)d_in[4];
    const float* bh = (const float*)d_in[5];
    const float* Wa = (const float*)d_in[6];
    const float* ba = (const float*)d_in[7];
    const float* Wp = (const float*)d_in[8];
    const float* bp = (const float*)d_in[9];
    float* out = (float*)d_out;

    dim3 grid(B_TOT / NS);   // 256 WGs x 4 waves: all CUs, 8 samples/block,
    dim3 block(256);         // 2 activation cells/lane (cols duplicated n<->n+8)
    lstm_v16_kernel<<<grid, block, 0, stream>>>(s, W0, b0, Wi, Wh, bh,
                                                Wa, ba, Wp, bp, out);
}